// Round 11
// baseline (281.760 us; speedup 1.0000x reference)
//
#include <hip/hip_runtime.h>

#define NB    8       // batches
#define NP    4096    // points per batch
#define KNN   20      // neighbors
#define COUT  64      // output channels
#define S     4       // candidate splits per query (r3-verified config)
#define BLK   256     // threads per block (4 waves)
#define QPB   (BLK / S)          // 64 queries per block
#define BPB   (NP / QPB)         // 64 blocks per batch
#define NBLK1 (NB * BPB)         // 512 blocks == 256 CUs x 2 blocks/CU (64KB LDS)
                                  // -> ALL blocks co-resident: grid barrier safe
#define NMOM  14
#define MSTR  16      // moment stride in floats: 64 B = one cache line per moment
#define LCAP  32      // padded list length for bitonic merge
#define FBIG  3.402823466e38f

typedef unsigned long long u64;
typedef unsigned int u32;

// strict-< sorted insert (ascending), insert-after-equals == lax.top_k's
// lowest-index-first tie-break (verified rounds 4/6/8/11/12/16/18). FBIG -> no-op.
__device__ __forceinline__ void ins20(float d, u32 mi,
                                      float* __restrict__ bd,
                                      u32* __restrict__ bi) {
#pragma unroll
    for (int j = KNN - 1; j >= 1; --j) {
        const bool sh  = d < bd[j - 1];
        const bool in_ = !sh && (d < bd[j]);
        bi[j] = sh ? bi[j - 1] : (in_ ? mi : bi[j]);
        bd[j] = fminf(fmaxf(bd[j - 1], d), bd[j]);   // med3
    }
    if (d < bd[0]) { bi[0] = mi; bd[0] = d; }
}

// reference-exact d2: base=add(qsq,csq); dot; fmaf(-2,dot,base).
// Deterministic on identical input bits (passed r9/r10).
__device__ __forceinline__ float d2_of(const float4 c, const float4 q) {
    const float base = __fadd_rn(q.w, c.w);
    const float dot  = fmaf(q.z, c.z, fmaf(q.y, c.y, __fmul_rn(q.x, c.x)));
    return fmaf(-2.0f, dot, base);
}

// ---- FUSED kernel (r11). Scan/flush/merge/epilogue byte-equivalent to the
// r10-verified knn (183.8us, passing); then, instead of writing idx and
// re-deriving everything in a second dispatch:
//   moments (same fp32 atomics) -> grid barrier (all 512 blocks co-resident
//   by pigeonhole: 64KB LDS caps 2 blocks/CU, 512 = 256x2) -> BN params in
//   LDS (aliased over dead sp) -> out phase using fx..fd STILL IN REGISTERS
//   (the epilogue computes them with out_kernel's exact op sequence).
// Removes: out dispatch + gap, idx round-trip, pos re-gather, per-block bn.
__global__ __launch_bounds__(BLK, 2)
void fused_kernel(const float* __restrict__ pos,
                  const float* __restrict__ W,
                  const float* __restrict__ bias,
                  const float* __restrict__ gamma,
                  const float* __restrict__ beta,
                  float* __restrict__ mom,
                  u32* __restrict__ ctr,
                  float* __restrict__ out) {
    __shared__ float4 sp[NP];                      // 64 KB: (x, y, z, csq)

    const int b = blockIdx.x / BPB;
    const int t = threadIdx.x;
    const int s = t & (S - 1);                     // my split
    const int n = (blockIdx.x % BPB) * QPB + (t >> 2);   // my query
    const float* pb = pos + (size_t)b * NP * 3;

    // stage pos[b]; csq computed with the reference's exact op sequence
    for (int i = t; i < NP; i += BLK) {
        const float x = pb[3 * i], y = pb[3 * i + 1], z = pb[3 * i + 2];
        const float csq = __fadd_rn(
            __fadd_rn(__fmul_rn(x, x), __fmul_rn(y, y)), __fmul_rn(z, z));
        sp[i] = make_float4(x, y, z, csq);
    }
    __syncthreads();

    const float4 q = sp[n];                        // qx,qy,qz,qsq (same bits)

    // ---- sample phase: tight certified initial bound (r3-verified) ----
    float sd0 = FBIG, sd1 = FBIG, sd2 = FBIG, sd3 = FBIG, sd4 = FBIG;
#pragma unroll 4
    for (int i = 0; i < NP / S; i += 4) {
        const int m = (i << 2) | s;
        const float d2 = d2_of(sp[m], q);
        if (m != n && d2 < sd4) {                  // 5-deep med3 insert (values)
            sd4 = fminf(fmaxf(sd3, d2), sd4);
            sd3 = fminf(fmaxf(sd2, d2), sd3);
            sd2 = fminf(fmaxf(sd1, d2), sd2);
            sd1 = fminf(fmaxf(sd0, d2), sd1);
            sd0 = fminf(sd0, d2);
        }
    }
    float gb = sd4;                                // my 5th-smallest sample
    gb = fmaxf(gb, __shfl_xor(gb, 1));             // group-max -> certified-20
    gb = fmaxf(gb, __shfl_xor(gb, 2));

    float bd[KNN];
    u32   bi[KNN];
#pragma unroll
    for (int j = 0; j < KNN; ++j) { bd[j] = FBIG; bi[j] = 0xFFFu; }
    u64 pidx = 0;                                  // 4x12-bit pending indices
    int cnt = 0;

#pragma unroll 4
    for (int i = 0; i < NP / S; ++i) {
        const int m = (i << 2) | s;
        const float d2 = d2_of(sp[m], q);          // 4 distinct addrs: broadcast
        // <=: rejection requires 20 STRICTLY better witnesses (index-free);
        // self (m==n) accepted here and FBIG'd at flush (r10-verified).
        const bool acc = (d2 <= gb);
        pidx = acc ? ((pidx << 12) | (u64)(u32)m) : pidx;  // newest in low bits
        cnt += (int)acc;
        if (__ballot(cnt == 4)) {                  // amortized wave-wide flush
            const u32 m3 = (u32)(pidx >> 36) & 0xFFFu;   // oldest (when cnt==4)
            const u32 m2 = (u32)(pidx >> 24) & 0xFFFu;
            const u32 m1 = (u32)(pidx >> 12) & 0xFFFu;
            const u32 m0 = (u32)pidx & 0xFFFu;           // newest
            const float d3r = d2_of(sp[m3], q);    // bit-exact recompute
            const float d2r = d2_of(sp[m2], q);
            const float d1r = d2_of(sp[m1], q);
            const float d0r = d2_of(sp[m0], q);
            // oldest-first drain; guards add self-exclusion (FBIG = no-op)
            ins20((cnt >= 4 && m3 != (u32)n) ? d3r : FBIG, m3, bd, bi);
            ins20((cnt >= 3 && m2 != (u32)n) ? d2r : FBIG, m2, bd, bi);
            ins20((cnt >= 2 && m1 != (u32)n) ? d1r : FBIG, m1, bd, bi);
            ins20((cnt >= 1 && m0 != (u32)n) ? d0r : FBIG, m0, bd, bi);
            cnt = 0; pidx = 0;
            // refresh group bound: two independent certified-20 terms (r6).
            float g = bd[KNN - 1];                 // min-over-lanes own-20th
            g = fminf(g, __shfl_xor(g, 1));
            g = fminf(g, __shfl_xor(g, 2));
            float g4 = bd[4];                      // max-over-lanes own-5th
            g4 = fmaxf(g4, __shfl_xor(g4, 1));     // 4 lanes x 5 accepts = 20
            g4 = fmaxf(g4, __shfl_xor(g4, 2));     // witnesses <= g4
            gb = fminf(gb, fminf(g, g4));          // only ever tightens
        }
    }
    {   // drain pending (oldest-first, same guards incl. self-exclusion)
        const u32 m3 = (u32)(pidx >> 36) & 0xFFFu;
        const u32 m2 = (u32)(pidx >> 24) & 0xFFFu;
        const u32 m1 = (u32)(pidx >> 12) & 0xFFFu;
        const u32 m0 = (u32)pidx & 0xFFFu;
        const float d3r = d2_of(sp[m3], q);
        const float d2r = d2_of(sp[m2], q);
        const float d1r = d2_of(sp[m1], q);
        const float d0r = d2_of(sp[m0], q);
        ins20((cnt >= 4 && m3 != (u32)n) ? d3r : FBIG, m3, bd, bi);
        ins20((cnt >= 3 && m2 != (u32)n) ? d2r : FBIG, m2, bd, bi);
        ins20((cnt >= 2 && m1 != (u32)n) ? d1r : FBIG, m1, bd, bi);
        ins20((cnt >= 1 && m0 != (u32)n) ? d0r : FBIG, m0, bd, bi);
    }

    // build merge keys: order-preserving float->uint flip,
    // idx in low 12 bits = lowest-index-first ties (verified r7/8/11/12/16/18)
    u64 key[LCAP];
#pragma unroll
    for (int j = 0; j < KNN; ++j) {
        u32 fb = __float_as_uint(bd[j]);
        fb ^= (u32)((int)fb >> 31) | 0x80000000u;
        key[j] = ((u64)fb << 12) | bi[j];
    }
#pragma unroll
    for (int j = KNN; j < LCAP; ++j) key[j] = ~0ull;

    // merge 4 split lists across lanes (verified bitonic merge)
#pragma unroll
    for (int r = 1; r <= 2; r <<= 1) {
#pragma unroll
        for (int j = 0; j < LCAP / 2; ++j) {
            const int k2 = LCAP - 1 - j;
            const u64 pa = (u64)__shfl_xor((long long)key[k2], r);
            const u64 pc = (u64)__shfl_xor((long long)key[j],  r);
            key[j]  = key[j]  < pa ? key[j]  : pa;
            key[k2] = key[k2] < pc ? key[k2] : pc;
        }
#pragma unroll
        for (int d = 16; d >= 1; d >>= 1) {
#pragma unroll
            for (int j = 0; j < LCAP; ++j) {
                if ((j & d) == 0) {
                    const u64 x = key[j], y = key[j + d];
                    key[j]     = x < y ? x : y;
                    key[j + d] = x < y ? y : x;
                }
            }
        }
    }

    // static-j epilogue: features kept in registers for the out phase.
    // dx..dd use out_kernel's exact op sequence on the same bits.
    float fx[KNN], fy[KNN], fz[KNN], fd[KNN];
    float s1x = 0, s1y = 0, s1z = 0, s1d = 0;
    float mxx = 0, mxy = 0, mxz = 0, mxd = 0;
    float myy = 0, myz = 0, myd = 0;
    float mzz = 0, mzd = 0, mdd = 0;
#pragma unroll
    for (int j = 0; j < KNN; ++j) {
        const int m = (int)(key[j] & 0xFFFull);
        const float4 c = sp[m];
        const float dx = __fsub_rn(c.x, q.x);
        const float dy = __fsub_rn(c.y, q.y);
        const float dz = __fsub_rn(c.z, q.z);
        const float dd = sqrtf(__fadd_rn(
            __fadd_rn(__fmul_rn(dx, dx), __fmul_rn(dy, dy)), __fmul_rn(dz, dz)));
        fx[j] = dx; fy[j] = dy; fz[j] = dz; fd[j] = dd;
        s1x += dx; s1y += dy; s1z += dz; s1d += dd;
        mxx += dx * dx; mxy += dx * dy; mxz += dx * dz; mxd += dx * dd;
        myy += dy * dy; myz += dy * dz; myd += dy * dd;
        mzz += dz * dz; mzd += dz * dd; mdd += dd * dd;
    }
    {
        // every query counted 4x (once per split lane) -> exact /4 after reduce.
        float vals[NMOM] = {s1x, s1y, s1z, s1d,
                            mxx, mxy, mxz, mxd, myy, myz, myd, mzz, mzd, mdd};
#pragma unroll
        for (int tt = 0; tt < NMOM; ++tt) {
            float v = vals[tt];
#pragma unroll
            for (int off = 32; off > 0; off >>= 1) v += __shfl_down(v, off);
            if ((t & 63) == 0) atomicAdd(&mom[tt * MSTR], v * 0.25f);
        }
    }

    // ---- grid barrier: all 512 blocks are co-resident (see NBLK1 note) ----
    __syncthreads();                 // whole block done: sp reads + mom atomics
    __threadfence();                 // device-visible before arrive
    if (t == 0) {
        __hip_atomic_fetch_add(ctr, 1u, __ATOMIC_ACQ_REL, __HIP_MEMORY_SCOPE_AGENT);
        while (__hip_atomic_load(ctr, __ATOMIC_ACQUIRE, __HIP_MEMORY_SCOPE_AGENT)
               < (u32)NBLK1) {
            __builtin_amdgcn_s_sleep(8);
        }
    }
    __syncthreads();                 // release whole block; sp now dead

    // ---- BN params (identical double pipeline), LDS aliased over sp ----
    float* lds = (float*)sp;
    float (*sWp)[4] = (float(*)[4])lds;            // 64 x 4 floats
    float*  sbp     = lds + COUT * 4;              // 64 floats
    if (t < COUT) {
        const int o = t;
        double S1[4], s2v[10];
#pragma unroll
        for (int tt = 0; tt < 4; ++tt)
            S1[tt] = (double)__hip_atomic_load(&mom[tt * MSTR],
                         __ATOMIC_RELAXED, __HIP_MEMORY_SCOPE_AGENT);
#pragma unroll
        for (int tt = 0; tt < 10; ++tt)
            s2v[tt] = (double)__hip_atomic_load(&mom[(4 + tt) * MSTR],
                          __ATOMIC_RELAXED, __HIP_MEMORY_SCOPE_AGENT);
        const double M = (double)NB * NP * KNN;
        double mean[4];
#pragma unroll
        for (int c = 0; c < 4; ++c) mean[c] = S1[c] / M;
        double E2[4][4];
        E2[0][0] = s2v[0]; E2[0][1] = E2[1][0] = s2v[1];
        E2[0][2] = E2[2][0] = s2v[2]; E2[0][3] = E2[3][0] = s2v[3];
        E2[1][1] = s2v[4]; E2[1][2] = E2[2][1] = s2v[5];
        E2[1][3] = E2[3][1] = s2v[6];
        E2[2][2] = s2v[7]; E2[2][3] = E2[3][2] = s2v[8];
        E2[3][3] = s2v[9];
        double w[4];
#pragma unroll
        for (int c = 0; c < 4; ++c) w[c] = (double)W[o * 4 + c];
        const double bo = (double)bias[o];
        double mu = bo;
#pragma unroll
        for (int c = 0; c < 4; ++c) mu += w[c] * mean[c];
        double var = 0.0;
#pragma unroll
        for (int c = 0; c < 4; ++c)
#pragma unroll
            for (int c2 = 0; c2 < 4; ++c2)
                var += w[c] * w[c2] * (E2[c][c2] / M - mean[c] * mean[c2]);
        const double scale = (double)gamma[o] / sqrt(var + 1e-5);
#pragma unroll
        for (int c = 0; c < 4; ++c) sWp[o][c] = (float)(w[c] * scale);
        sbp[o] = (float)((bo - mu) * scale + (double)beta[o]);
    }
    __syncthreads();

    // ---- out phase: my query n, my 16 channels (c0 = s*16), fx..fd in regs.
    // fmaf chain + j-order identical to the verified out_kernel.
    const int c0 = s * 16;
    float* ob = out + ((size_t)b * NP + n) * COUT + c0;
    const float inv = 1.0f / (float)KNN;
#pragma unroll
    for (int o = 0; o < 16; o += 4) {
        float acc[4];
#pragma unroll
        for (int qq = 0; qq < 4; ++qq) {
            const float w0 = sWp[c0 + o + qq][0], w1 = sWp[c0 + o + qq][1];
            const float w2 = sWp[c0 + o + qq][2], w3 = sWp[c0 + o + qq][3];
            const float bb = sbp[c0 + o + qq];
            float a = 0.f;
#pragma unroll
            for (int j = 0; j < KNN; ++j) {
                float y = fmaf(fx[j], w0,
                          fmaf(fy[j], w1, fmaf(fz[j], w2, fmaf(fd[j], w3, bb))));
                a += fmaxf(y, 0.f);
            }
            acc[qq] = a * inv;
        }
        float4 p = {acc[0], acc[1], acc[2], acc[3]};
        *reinterpret_cast<float4*>(ob + o) = p;
    }
}

extern "C" void kernel_launch(void* const* d_in, const int* in_sizes, int n_in,
                              void* d_out, int out_size, void* d_ws, size_t ws_size,
                              hipStream_t stream) {
    (void)in_sizes; (void)n_in; (void)out_size; (void)ws_size;
    const float* pos   = (const float*)d_in[1];   // d_in[0] = x (unused by math)
    const float* W     = (const float*)d_in[2];
    const float* bias  = (const float*)d_in[3];
    const float* gamma = (const float*)d_in[4];
    const float* beta  = (const float*)d_in[5];
    float* out = (float*)d_out;

    float* mom = (float*)d_ws;                     // 14 x 64 B at offset 0
    u32*   ctr = (u32*)((char*)d_ws + 960);        // barrier counter

    hipMemsetAsync(d_ws, 0, 1024, stream);         // zero mom + ctr each replay
    fused_kernel<<<NBLK1, BLK, 0, stream>>>(pos, W, bias, gamma, beta,
                                            mom, ctr, out);
}

// Round 13
// 250.093 us; speedup vs baseline: 1.1266x; 1.1266x over previous
//
#include <hip/hip_runtime.h>

#define NB    8       // batches
#define NP    4096    // points per batch
#define KNN   20      // neighbors
#define COUT  64      // output channels
#define S     4       // candidate splits per query (r3-verified config)
#define BLK   256     // threads per block (4 waves)
#define QPB   (BLK / S)          // 64 queries per block
#define BPB   (NP / QPB)         // 64 blocks per batch
#define NBLK1 (NB * BPB)         // 512 blocks
#define NBLK2 ((NB * NP * 4) / BLK)   // 512 blocks (4 threads per query)
#define NBKT  64      // x buckets for the window scan
#define NMOM  14
#define MSTR  16      // moment stride in floats: 64 B = one cache line per moment
#define LCAP  32      // padded list length for bitonic merge
#define FBIG  3.402823466e38f
// key with dist bits = flip(FBIG): unflips to FBIG (keeps g/g4 certificates
// sound) and is > every real key -> also the merge pad. 56-bit keys.
#define KBIG  ((u64)0xFF7FFFFFull << 24 | 0xFFFFFFull)

typedef unsigned long long u64;
typedef unsigned int u32;
typedef unsigned short u16;

// sorted insert of unique u64 keys, strict <, ascending. KBIG -> no-op.
// key = (flip(d2) << 24) | (orig_idx << 12) | sorted_m : ordering is
// (d2, orig idx) lexicographic == lax.top_k's lowest-index-first tie-break,
// INDEPENDENT of scan order (keys unique -> no equal case).
__device__ __forceinline__ void kins20(u64 k, u64* __restrict__ kbd) {
#pragma unroll
    for (int j = KNN - 1; j >= 1; --j) {
        const bool sh  = k < kbd[j - 1];
        const bool in_ = !sh && (k < kbd[j]);
        kbd[j] = sh ? kbd[j - 1] : (in_ ? k : kbd[j]);
    }
    if (k < kbd[0]) kbd[0] = k;
}

// reference-exact d2 (passed r9/r10/r11): deterministic on identical bits.
__device__ __forceinline__ float d2_of(const float4 c, const float4 q) {
    const float base = __fadd_rn(q.w, c.w);
    const float dot  = fmaf(q.z, c.z, fmaf(q.y, c.y, __fmul_rn(q.x, c.x)));
    return fmaf(-2.0f, dot, base);
}

__device__ __forceinline__ u64 mk_key(float d, u32 orig, u32 ms) {
    u32 fb = __float_as_uint(d);
    fb ^= (u32)((int)fb >> 31) | 0x80000000u;      // order-preserving flip
    return ((u64)fb << 24) | ((u64)orig << 12) | (u64)ms;
}
__device__ __forceinline__ float kdist(u64 k) {    // inverse flip of dist bits
    u32 v = (u32)(k >> 24);
    v = (v & 0x80000000u) ? (v ^ 0x80000000u) : ~v;
    return __uint_as_float(v);
}

// ---- Kernel 0 (r12): per-batch counting sort into 64 x-buckets ---------
// Scatter order within a bucket is nondeterministic (LDS atomics); harmless:
// top-20 selection is order-independent (key-based, certified-witness
// rejection), so outputs stay deterministic.
__global__ __launch_bounds__(BLK)
void sort_kernel(const float* __restrict__ pos,
                 float4* __restrict__ f4o,
                 u16* __restrict__ idxo,
                 u32* __restrict__ bstart) {
    __shared__ u32 hist[NBKT];
    __shared__ u32 base[NBKT + 1];
    const int b = blockIdx.x;
    const int t = threadIdx.x;
    const float* pb = pos + (size_t)b * NP * 3;

    if (t < NBKT) hist[t] = 0;
    __syncthreads();

    float px[NP / BLK], py[NP / BLK], pz[NP / BLK];
    int   bu[NP / BLK];
#pragma unroll
    for (int k = 0; k < NP / BLK; ++k) {
        const int i = t + k * BLK;
        px[k] = pb[3 * i]; py[k] = pb[3 * i + 1]; pz[k] = pb[3 * i + 2];
        int bb = (int)(px[k] * (float)NBKT);
        bb = bb < 0 ? 0 : (bb > NBKT - 1 ? NBKT - 1 : bb);
        bu[k] = bb;
        atomicAdd(&hist[bb], 1u);
    }
    __syncthreads();
    if (t == 0) {
        u32 acc = 0;
#pragma unroll
        for (int j = 0; j < NBKT; ++j) { base[j] = acc; acc += hist[j]; }
        base[NBKT] = acc;                          // == NP
    }
    __syncthreads();
    if (t < NBKT) hist[t] = base[t];               // running cursors
    __syncthreads();
#pragma unroll
    for (int k = 0; k < NP / BLK; ++k) {
        const u32 p = atomicAdd(&hist[bu[k]], 1u);
        const float csq = __fadd_rn(__fadd_rn(__fmul_rn(px[k], px[k]),
                          __fmul_rn(py[k], py[k])), __fmul_rn(pz[k], pz[k]));
        f4o[(size_t)b * NP + p]  = make_float4(px[k], py[k], pz[k], csq);
        idxo[(size_t)b * NP + p] = (u16)(t + k * BLK);
    }
    if (t <= NBKT) bstart[b * (NBKT + 1) + t] = base[t];
}

// ---- Kernel 1: KNN over the x-window of the bucket-sorted array --------
// r10-verified scan/flush/refresh/merge/moment structure; lists are u64
// keys (order-robust tie-break); scan range limited to buckets covering
// [qx - r, qx + r], r = sqrtf(gb + 1e-4f) from the certified sample bound
// (margin >> d2 cancellation error ~4e-7; bucketization monotone in fp32).
__global__ __launch_bounds__(BLK, 2)
void knn_kernel(const float* __restrict__ pos,
                const float4* __restrict__ f4in,
                const u16* __restrict__ idxin,
                const u32* __restrict__ bstart,
                unsigned short* __restrict__ idx_out,
                float* __restrict__ mom) {
    __shared__ float4 sp[NP + 4];                  // +4: unroll overshoot pad
    __shared__ u16 sidx[NP];
    __shared__ u32 sb[NBKT + 1];

    const int b = blockIdx.x / BPB;
    const int t = threadIdx.x;
    const int s = t & (S - 1);                     // my split
    const int n = (blockIdx.x % BPB) * QPB + (t >> 2);   // my query (orig idx)
    const float* pb = pos + (size_t)b * NP * 3;

    for (int i = t; i < NP; i += BLK) sp[i] = f4in[(size_t)b * NP + i];
    if (t < 4) sp[NP + t] = make_float4(0.f, 0.f, 0.f, 0.f);   // init pad
    for (int i = t; i < NP / 2; i += BLK)          // u16 pairs as u32
        ((u32*)sidx)[i] = ((const u32*)(idxin + (size_t)b * NP))[i];
    if (t <= NBKT) sb[t] = bstart[b * (NBKT + 1) + t];
    __syncthreads();

    // q from original pos; csq with the reference op sequence (same bits
    // as the staged copies).
    const float qx = pb[3 * n], qy = pb[3 * n + 1], qz = pb[3 * n + 2];
    const float qsq = __fadd_rn(
        __fadd_rn(__fmul_rn(qx, qx), __fmul_rn(qy, qy)), __fmul_rn(qz, qz));
    const float4 q = make_float4(qx, qy, qz, qsq);

    // ---- sample phase: certified-20 bound (verified 5-deep x 4-lane shape),
    // strided over the sorted array; self excluded via orig idx.
    float sd0 = FBIG, sd1 = FBIG, sd2 = FBIG, sd3 = FBIG, sd4 = FBIG;
#pragma unroll 4
    for (int i = 0; i < NP / S; i += 4) {
        const int m = (i << 2) | s;
        const float d2 = d2_of(sp[m], q);
        if (sidx[m] != (u16)n && d2 < sd4) {       // 5-deep med3 insert
            sd4 = fminf(fmaxf(sd3, d2), sd4);
            sd3 = fminf(fmaxf(sd2, d2), sd3);
            sd2 = fminf(fmaxf(sd1, d2), sd2);
            sd1 = fminf(fmaxf(sd0, d2), sd1);
            sd0 = fminf(sd0, d2);
        }
    }
    float gb = sd4;                                // my 5th-smallest sample
    gb = fmaxf(gb, __shfl_xor(gb, 1));             // group-max -> certified-20
    gb = fmaxf(gb, __shfl_xor(gb, 2));

    // ---- x-window from the certified bound (group-uniform) ----
    const float r = sqrtf(__fadd_rn(gb, 1e-4f));
    int bl = (int)(__fsub_rn(qx, r) * (float)NBKT);
    int bh = (int)(__fadd_rn(qx, r) * (float)NBKT);
    bl = bl < 0 ? 0 : bl;  bh = bh > NBKT - 1 ? NBKT - 1 : bh;
    const int lo = (int)sb[bl], hi = (int)sb[bh + 1];
    const int nit = (hi - lo + S - 1) >> 2;        // group-uniform trip count

    u64 kbd[KNN];
#pragma unroll
    for (int j = 0; j < KNN; ++j) kbd[j] = KBIG;
    u64 pidx = 0;                                  // 4x12-bit pending (sorted m)
    int cnt = 0;

#pragma unroll 4
    for (int k = 0; k < nit; ++k) {
        const int m = lo + (k << 2) + s;           // may overshoot hi by <4
        const float d2 = d2_of(sp[m], q);          // pad slots: zeros, m>=hi
        // <=: rejection needs 20 strictly-better certified witnesses;
        // self accepted here, excluded at flush (r10-verified pattern).
        const bool acc = (m < hi) && (d2 <= gb);
        pidx = acc ? ((pidx << 12) | (u64)(u32)m) : pidx;
        cnt += (int)acc;
        if (__ballot(cnt == 4)) {                  // amortized wave-wide flush
            const u32 m3 = (u32)(pidx >> 36) & 0xFFFu;   // oldest
            const u32 m2 = (u32)(pidx >> 24) & 0xFFFu;
            const u32 m1 = (u32)(pidx >> 12) & 0xFFFu;
            const u32 m0 = (u32)pidx & 0xFFFu;           // newest
            const u32 o3 = sidx[m3], o2 = sidx[m2], o1 = sidx[m1], o0 = sidx[m0];
            const u64 k3 = (cnt >= 4 && o3 != (u32)n)
                               ? mk_key(d2_of(sp[m3], q), o3, m3) : KBIG;
            const u64 k2 = (cnt >= 3 && o2 != (u32)n)
                               ? mk_key(d2_of(sp[m2], q), o2, m2) : KBIG;
            const u64 k1 = (cnt >= 2 && o1 != (u32)n)
                               ? mk_key(d2_of(sp[m1], q), o1, m1) : KBIG;
            const u64 k0 = (cnt >= 1 && o0 != (u32)n)
                               ? mk_key(d2_of(sp[m0], q), o0, m0) : KBIG;
            kins20(k3, kbd); kins20(k2, kbd);      // oldest-first drain
            kins20(k1, kbd); kins20(k0, kbd);
            cnt = 0; pidx = 0;
            // refresh: two certified-20 terms (r6-verified logic).
            float g = kdist(kbd[KNN - 1]);         // min-over-lanes own-20th
            g = fminf(g, __shfl_xor(g, 1));
            g = fminf(g, __shfl_xor(g, 2));
            float g4 = kdist(kbd[4]);              // max-over-lanes own-5th
            g4 = fmaxf(g4, __shfl_xor(g4, 1));     // 4 lanes x 5 accepts = 20
            g4 = fmaxf(g4, __shfl_xor(g4, 2));
            gb = fminf(gb, fminf(g, g4));          // only ever tightens
        }
    }
    {   // drain pending (oldest-first, same guards)
        const u32 m3 = (u32)(pidx >> 36) & 0xFFFu;
        const u32 m2 = (u32)(pidx >> 24) & 0xFFFu;
        const u32 m1 = (u32)(pidx >> 12) & 0xFFFu;
        const u32 m0 = (u32)pidx & 0xFFFu;
        const u32 o3 = sidx[m3], o2 = sidx[m2], o1 = sidx[m1], o0 = sidx[m0];
        const u64 k3 = (cnt >= 4 && o3 != (u32)n)
                           ? mk_key(d2_of(sp[m3], q), o3, m3) : KBIG;
        const u64 k2 = (cnt >= 3 && o2 != (u32)n)
                           ? mk_key(d2_of(sp[m2], q), o2, m2) : KBIG;
        const u64 k1 = (cnt >= 2 && o1 != (u32)n)
                           ? mk_key(d2_of(sp[m1], q), o1, m1) : KBIG;
        const u64 k0 = (cnt >= 1 && o0 != (u32)n)
                           ? mk_key(d2_of(sp[m0], q), o0, m0) : KBIG;
        kins20(k3, kbd); kins20(k2, kbd); kins20(k1, kbd); kins20(k0, kbd);
    }

    // merge 4 split lists across lanes (verified bitonic min-merge);
    // kbd already IS the key list, ascending; pad with KBIG.
    u64 key[LCAP];
#pragma unroll
    for (int j = 0; j < KNN; ++j) key[j] = kbd[j];
#pragma unroll
    for (int j = KNN; j < LCAP; ++j) key[j] = KBIG;

#pragma unroll
    for (int r2 = 1; r2 <= 2; r2 <<= 1) {
#pragma unroll
        for (int j = 0; j < LCAP / 2; ++j) {
            const int k2i = LCAP - 1 - j;
            const u64 pa = (u64)__shfl_xor((long long)key[k2i], r2);
            const u64 pc = (u64)__shfl_xor((long long)key[j],  r2);
            key[j]   = key[j]   < pa ? key[j]   : pa;
            key[k2i] = key[k2i] < pc ? key[k2i] : pc;
        }
#pragma unroll
        for (int d = 16; d >= 1; d >>= 1) {
#pragma unroll
            for (int j = 0; j < LCAP; ++j) {
                if ((j & d) == 0) {
                    const u64 x = key[j], y = key[j + d];
                    key[j]     = x < y ? x : y;
                    key[j + d] = x < y ? y : x;
                }
            }
        }
    }

    // static-j epilogue: orig idx for output, sorted m for coords.
    unsigned short* ip = idx_out + ((size_t)b * NP + n) * KNN;
    float s1x = 0, s1y = 0, s1z = 0, s1d = 0;
    float mxx = 0, mxy = 0, mxz = 0, mxd = 0;
    float myy = 0, myz = 0, myd = 0;
    float mzz = 0, mzd = 0, mdd = 0;
#pragma unroll
    for (int j = 0; j < KNN; ++j) {
        const int ms = (int)(key[j] & 0xFFFull);
        const int og = (int)((key[j] >> 12) & 0xFFFull);
        if ((j & 3) == s) ip[j] = (unsigned short)og;  // one lane per j
        const float4 c = sp[ms];
        const float dx = __fsub_rn(c.x, q.x);
        const float dy = __fsub_rn(c.y, q.y);
        const float dz = __fsub_rn(c.z, q.z);
        const float dd = sqrtf(__fadd_rn(
            __fadd_rn(__fmul_rn(dx, dx), __fmul_rn(dy, dy)), __fmul_rn(dz, dz)));
        s1x += dx; s1y += dy; s1z += dz; s1d += dd;
        mxx += dx * dx; mxy += dx * dy; mxz += dx * dz; mxd += dx * dd;
        myy += dy * dy; myz += dy * dz; myd += dy * dd;
        mzz += dz * dz; mzd += dz * dd; mdd += dd * dd;
    }
    {
        // every query counted 4x -> exact /4 after reduce; one cache line
        // per moment so the atomic queues parallelize.
        float vals[NMOM] = {s1x, s1y, s1z, s1d,
                            mxx, mxy, mxz, mxd, myy, myz, myd, mzz, mzd, mdd};
#pragma unroll
        for (int tt = 0; tt < NMOM; ++tt) {
            float v = vals[tt];
#pragma unroll
            for (int off = 32; off > 0; off >>= 1) v += __shfl_down(v, off);
            if ((t & 63) == 0) atomicAdd(&mom[tt * MSTR], v * 0.25f);
        }
    }
}

// ---------------- Kernel 2: r6 verbatim (best-known: out ~10us) ----------
__global__ __launch_bounds__(BLK)
void out_kernel(const float* __restrict__ pos,
                const float* __restrict__ W,
                const float* __restrict__ bias,
                const float* __restrict__ gamma,
                const float* __restrict__ beta,
                const unsigned short* __restrict__ idx_in,
                const float* __restrict__ mom,
                float* __restrict__ out) {
    __shared__ float sWp[COUT][4];
    __shared__ float sbp[COUT];

    if (threadIdx.x < COUT) {
        const int o = threadIdx.x;
        double S1[4], s2v[10];
#pragma unroll
        for (int tt = 0; tt < 4; ++tt)  S1[tt]  = (double)mom[tt * MSTR];
#pragma unroll
        for (int tt = 0; tt < 10; ++tt) s2v[tt] = (double)mom[(4 + tt) * MSTR];
        const double M = (double)NB * NP * KNN;
        double mean[4];
#pragma unroll
        for (int c = 0; c < 4; ++c) mean[c] = S1[c] / M;
        double E2[4][4];
        E2[0][0] = s2v[0]; E2[0][1] = E2[1][0] = s2v[1];
        E2[0][2] = E2[2][0] = s2v[2]; E2[0][3] = E2[3][0] = s2v[3];
        E2[1][1] = s2v[4]; E2[1][2] = E2[2][1] = s2v[5];
        E2[1][3] = E2[3][1] = s2v[6];
        E2[2][2] = s2v[7]; E2[2][3] = E2[3][2] = s2v[8];
        E2[3][3] = s2v[9];
        double w[4];
#pragma unroll
        for (int c = 0; c < 4; ++c) w[c] = (double)W[o * 4 + c];
        const double bo = (double)bias[o];
        double mu = bo;
#pragma unroll
        for (int c = 0; c < 4; ++c) mu += w[c] * mean[c];
        double var = 0.0;
#pragma unroll
        for (int c = 0; c < 4; ++c)
#pragma unroll
            for (int c2 = 0; c2 < 4; ++c2)
                var += w[c] * w[c2] * (E2[c][c2] / M - mean[c] * mean[c2]);
        const double scale = (double)gamma[o] / sqrt(var + 1e-5);
#pragma unroll
        for (int c = 0; c < 4; ++c) sWp[o][c] = (float)(w[c] * scale);
        sbp[o] = (float)((bo - mu) * scale + (double)beta[o]);
    }
    __syncthreads();

    const int t  = threadIdx.x;
    const int gq = blockIdx.x * (BLK / 4) + (t >> 2);  // global query
    const int b  = gq / NP, n = gq % NP;
    const int c0 = (t & 3) * 16;                       // my 16 channels
    const float* pb = pos + (size_t)b * NP * 3;
    const float qx = pb[3 * n], qy = pb[3 * n + 1], qz = pb[3 * n + 2];

    float fx[KNN], fy[KNN], fz[KNN], fd[KNN];
    const unsigned short* ip = idx_in + (size_t)gq * KNN;
#pragma unroll
    for (int j = 0; j < KNN; ++j) {
        const int m = ip[j];
        const float dx = __fsub_rn(pb[3 * m], qx);
        const float dy = __fsub_rn(pb[3 * m + 1], qy);
        const float dz = __fsub_rn(pb[3 * m + 2], qz);
        fx[j] = dx; fy[j] = dy; fz[j] = dz;
        fd[j] = sqrtf(__fadd_rn(
            __fadd_rn(__fmul_rn(dx, dx), __fmul_rn(dy, dy)), __fmul_rn(dz, dz)));
    }

    float* ob = out + (size_t)gq * COUT + c0;
    const float inv = 1.0f / (float)KNN;
#pragma unroll
    for (int o = 0; o < 16; o += 4) {
        float acc[4];
#pragma unroll
        for (int qq = 0; qq < 4; ++qq) {
            const float w0 = sWp[c0 + o + qq][0], w1 = sWp[c0 + o + qq][1];
            const float w2 = sWp[c0 + o + qq][2], w3 = sWp[c0 + o + qq][3];
            const float bb = sbp[c0 + o + qq];
            float a = 0.f;
#pragma unroll
            for (int j = 0; j < KNN; ++j) {
                float y = fmaf(fx[j], w0,
                          fmaf(fy[j], w1, fmaf(fz[j], w2, fmaf(fd[j], w3, bb))));
                a += fmaxf(y, 0.f);
            }
            acc[qq] = a * inv;
        }
        float4 p = {acc[0], acc[1], acc[2], acc[3]};
        *reinterpret_cast<float4*>(ob + o) = p;
    }
}

extern "C" void kernel_launch(void* const* d_in, const int* in_sizes, int n_in,
                              void* d_out, int out_size, void* d_ws, size_t ws_size,
                              hipStream_t stream) {
    (void)in_sizes; (void)n_in; (void)out_size; (void)ws_size;
    const float* pos   = (const float*)d_in[1];   // d_in[0] = x (unused by math)
    const float* W     = (const float*)d_in[2];
    const float* bias  = (const float*)d_in[3];
    const float* gamma = (const float*)d_in[4];
    const float* beta  = (const float*)d_in[5];
    float* out = (float*)d_out;

    // ws layout: [0,1024) mom | [1024,5120) bstart | [5120,+512K) f4 |
    //            then u16 sorted-orig-idx (64K) | then knn idx out (1.31MB)
    //            total ~1.9MB << ws (>=10.5MB proven in r8)
    float* mom   = (float*)d_ws;
    u32*   bstart = (u32*)((char*)d_ws + 1024);
    float4* f4s  = (float4*)((char*)d_ws + 5120);
    u16*   sidx  = (u16*)((char*)d_ws + 5120 + (size_t)NB * NP * sizeof(float4));
    unsigned short* idxws = (unsigned short*)((char*)sidx + (size_t)NB * NP * sizeof(u16));

    hipMemsetAsync(mom, 0, NMOM * MSTR * sizeof(float), stream);
    sort_kernel<<<NB, BLK, 0, stream>>>(pos, f4s, sidx, bstart);
    knn_kernel<<<NBLK1, BLK, 0, stream>>>(pos, f4s, sidx, bstart, idxws, mom);
    out_kernel<<<NBLK2, BLK, 0, stream>>>(pos, W, bias, gamma, beta,
                                          idxws, mom, out);
}

// Round 17
// 246.979 us; speedup vs baseline: 1.1408x; 1.0126x over previous
//
#include <hip/hip_runtime.h>

#define NB    8       // batches
#define NP    4096    // points per batch
#define KNN   20      // neighbors
#define COUT  64      // output channels
#define S     4       // candidate splits per query (r3-verified config)
#define BLK   256     // threads per block (4 waves)
#define QPB   (BLK / S)          // 64 queries per block
#define BPB   (NP / QPB)         // 64 blocks per batch
#define NBLK1 (NB * BPB)         // 512 blocks
#define NBLK2 ((NB * NP * 4) / BLK)   // 512 blocks (4 threads per query)
#define NMOM  14
#define MSTR  16      // moment stride in floats: 64 B = one cache line per moment
#define LCAP  32      // padded list length for bitonic merge
#define FBIG  3.402823466e38f

typedef unsigned long long u64;
typedef unsigned int u32;

// strict-< sorted insert (ascending), insert-after-equals == lax.top_k's
// lowest-index-first tie-break (verified r3/r6/r9/r10). FBIG -> no-op.
__device__ __forceinline__ void ins20(float d, u32 mi,
                                      float* __restrict__ bd,
                                      u32* __restrict__ bi) {
#pragma unroll
    for (int j = KNN - 1; j >= 1; --j) {
        const bool sh  = d < bd[j - 1];
        const bool in_ = !sh && (d < bd[j]);
        bi[j] = sh ? bi[j - 1] : (in_ ? mi : bi[j]);
        bd[j] = fminf(fmaxf(bd[j - 1], d), bd[j]);   // med3
    }
    if (d < bd[0]) { bi[0] = mi; bd[0] = d; }
}

// reference-exact d2: base=add(qsq,csq); dot; fmaf(-2,dot,base).
// Deterministic on identical input bits -> flush-time recompute is
// bit-identical to scan-time value (passed r9/r10).
__device__ __forceinline__ float d2_of(const float4 c, const float4 q) {
    const float base = __fadd_rn(q.w, c.w);
    const float dot  = fmaf(q.z, c.z, fmaf(q.y, c.y, __fmul_rn(q.x, c.x)));
    return fmaf(-2.0f, dot, base);
}

// ---- Kernel 1: KNN. r10-verified body (183.8us, 247.46 total). r17:
// sample loop unroll 4->8 ONLY (scheduling change, serial insert chain
// preserved). S=8 and window-scan directions are closed: 4 variants failed
// verification with an identical, audit-resistant absmax signature.
__global__ __launch_bounds__(BLK, 2)
void knn_kernel(const float* __restrict__ pos,
                unsigned short* __restrict__ idx_out,
                float* __restrict__ mom) {
    __shared__ float4 sp[NP];                      // 64 KB: (x, y, z, csq)

    const int b = blockIdx.x / BPB;
    const int t = threadIdx.x;
    const int s = t & (S - 1);                     // my split
    const int n = (blockIdx.x % BPB) * QPB + (t >> 2);   // my query
    const float* pb = pos + (size_t)b * NP * 3;

    // stage pos[b]; csq computed with the reference's exact op sequence
    for (int i = t; i < NP; i += BLK) {
        const float x = pb[3 * i], y = pb[3 * i + 1], z = pb[3 * i + 2];
        const float csq = __fadd_rn(
            __fadd_rn(__fmul_rn(x, x), __fmul_rn(y, y)), __fmul_rn(z, z));
        sp[i] = make_float4(x, y, z, csq);
    }
    __syncthreads();

    const float4 q = sp[n];                        // qx,qy,qz,qsq (same bits)

    // ---- sample phase: tight certified initial bound (r3-verified) ----
    float sd0 = FBIG, sd1 = FBIG, sd2 = FBIG, sd3 = FBIG, sd4 = FBIG;
#pragma unroll 8
    for (int i = 0; i < NP / S; i += 4) {
        const int m = (i << 2) | s;
        const float d2 = d2_of(sp[m], q);
        if (m != n && d2 < sd4) {                  // 5-deep med3 insert (values)
            sd4 = fminf(fmaxf(sd3, d2), sd4);
            sd3 = fminf(fmaxf(sd2, d2), sd3);
            sd2 = fminf(fmaxf(sd1, d2), sd2);
            sd1 = fminf(fmaxf(sd0, d2), sd1);
            sd0 = fminf(sd0, d2);
        }
    }
    float gb = sd4;                                // my 5th-smallest sample
    gb = fmaxf(gb, __shfl_xor(gb, 1));             // group-max -> certified-20
    gb = fmaxf(gb, __shfl_xor(gb, 2));

    float bd[KNN];
    u32   bi[KNN];
#pragma unroll
    for (int j = 0; j < KNN; ++j) { bd[j] = FBIG; bi[j] = 0xFFFu; }
    u64 pidx = 0;                                  // 4x12-bit pending indices
    int cnt = 0;

#pragma unroll 4
    for (int i = 0; i < NP / S; ++i) {
        const int m = (i << 2) | s;
        const float d2 = d2_of(sp[m], q);          // 4 distinct addrs: broadcast
        // <=: rejection requires 20 STRICTLY better witnesses (index-free);
        // self (m==n) is accepted here and FBIG'd at flush (r10-verified).
        const bool acc = (d2 <= gb);
        pidx = acc ? ((pidx << 12) | (u64)(u32)m) : pidx;  // newest in low bits
        cnt += (int)acc;
        if (__ballot(cnt == 4)) {                  // amortized wave-wide flush
            const u32 m3 = (u32)(pidx >> 36) & 0xFFFu;   // oldest (when cnt==4)
            const u32 m2 = (u32)(pidx >> 24) & 0xFFFu;
            const u32 m1 = (u32)(pidx >> 12) & 0xFFFu;
            const u32 m0 = (u32)pidx & 0xFFFu;           // newest
            const float d3r = d2_of(sp[m3], q);    // bit-exact recompute
            const float d2r = d2_of(sp[m2], q);
            const float d1r = d2_of(sp[m1], q);
            const float d0r = d2_of(sp[m0], q);
            // oldest-first drain; guards add self-exclusion (FBIG = no-op)
            ins20((cnt >= 4 && m3 != (u32)n) ? d3r : FBIG, m3, bd, bi);
            ins20((cnt >= 3 && m2 != (u32)n) ? d2r : FBIG, m2, bd, bi);
            ins20((cnt >= 2 && m1 != (u32)n) ? d1r : FBIG, m1, bd, bi);
            ins20((cnt >= 1 && m0 != (u32)n) ? d0r : FBIG, m0, bd, bi);
            cnt = 0; pidx = 0;
            // refresh group bound: two independent certified-20 terms (r6).
            float g = bd[KNN - 1];                 // min-over-lanes own-20th
            g = fminf(g, __shfl_xor(g, 1));
            g = fminf(g, __shfl_xor(g, 2));
            float g4 = bd[4];                      // max-over-lanes own-5th
            g4 = fmaxf(g4, __shfl_xor(g4, 1));     // 4 lanes x 5 accepts = 20
            g4 = fmaxf(g4, __shfl_xor(g4, 2));     // witnesses <= g4
            gb = fminf(gb, fminf(g, g4));          // only ever tightens
        }
    }
    {   // drain pending (oldest-first, same guards incl. self-exclusion)
        const u32 m3 = (u32)(pidx >> 36) & 0xFFFu;
        const u32 m2 = (u32)(pidx >> 24) & 0xFFFu;
        const u32 m1 = (u32)(pidx >> 12) & 0xFFFu;
        const u32 m0 = (u32)pidx & 0xFFFu;
        const float d3r = d2_of(sp[m3], q);
        const float d2r = d2_of(sp[m2], q);
        const float d1r = d2_of(sp[m1], q);
        const float d0r = d2_of(sp[m0], q);
        ins20((cnt >= 4 && m3 != (u32)n) ? d3r : FBIG, m3, bd, bi);
        ins20((cnt >= 3 && m2 != (u32)n) ? d2r : FBIG, m2, bd, bi);
        ins20((cnt >= 2 && m1 != (u32)n) ? d1r : FBIG, m1, bd, bi);
        ins20((cnt >= 1 && m0 != (u32)n) ? d0r : FBIG, m0, bd, bi);
    }

    // build merge keys: order-preserving float->uint flip,
    // idx in low 12 bits = lowest-index-first ties (verified)
    u64 key[LCAP];
#pragma unroll
    for (int j = 0; j < KNN; ++j) {
        u32 fb = __float_as_uint(bd[j]);
        fb ^= (u32)((int)fb >> 31) | 0x80000000u;
        key[j] = ((u64)fb << 12) | bi[j];
    }
#pragma unroll
    for (int j = KNN; j < LCAP; ++j) key[j] = ~0ull;

    // merge 4 split lists across lanes (verified bitonic merge)
#pragma unroll
    for (int r = 1; r <= 2; r <<= 1) {
#pragma unroll
        for (int j = 0; j < LCAP / 2; ++j) {
            const int k2 = LCAP - 1 - j;
            const u64 pa = (u64)__shfl_xor((long long)key[k2], r);
            const u64 pc = (u64)__shfl_xor((long long)key[j],  r);
            key[j]  = key[j]  < pa ? key[j]  : pa;
            key[k2] = key[k2] < pc ? key[k2] : pc;
        }
#pragma unroll
        for (int d = 16; d >= 1; d >>= 1) {
#pragma unroll
            for (int j = 0; j < LCAP; ++j) {
                if ((j & d) == 0) {
                    const u64 x = key[j], y = key[j + d];
                    key[j]     = x < y ? x : y;
                    key[j + d] = x < y ? y : x;
                }
            }
        }
    }

    // static-j epilogue (verified; no dynamic reg indexing)
    unsigned short* ip = idx_out + ((size_t)b * NP + n) * KNN;
    float s1x = 0, s1y = 0, s1z = 0, s1d = 0;
    float mxx = 0, mxy = 0, mxz = 0, mxd = 0;
    float myy = 0, myz = 0, myd = 0;
    float mzz = 0, mzd = 0, mdd = 0;
#pragma unroll
    for (int j = 0; j < KNN; ++j) {
        const int m = (int)(key[j] & 0xFFFull);
        if ((j & 3) == s) ip[j] = (unsigned short)m;   // one lane per j
        const float4 c = sp[m];
        const float dx = __fsub_rn(c.x, q.x);
        const float dy = __fsub_rn(c.y, q.y);
        const float dz = __fsub_rn(c.z, q.z);
        const float dd = sqrtf(__fadd_rn(
            __fadd_rn(__fmul_rn(dx, dx), __fmul_rn(dy, dy)), __fmul_rn(dz, dz)));
        s1x += dx; s1y += dy; s1z += dz; s1d += dd;
        mxx += dx * dx; mxy += dx * dy; mxz += dx * dz; mxd += dx * dd;
        myy += dy * dy; myz += dy * dz; myd += dy * dd;
        mzz += dz * dz; mzd += dz * dd; mdd += dd * dd;
    }
    {
        // every query counted 4x (once per split lane) -> exact /4 after reduce.
        // each moment gets its OWN cache line (mom[tt*16]) so the same-address
        // atomic queues run in parallel across 14 lines.
        float vals[NMOM] = {s1x, s1y, s1z, s1d,
                            mxx, mxy, mxz, mxd, myy, myz, myd, mzz, mzd, mdd};
#pragma unroll
        for (int tt = 0; tt < NMOM; ++tt) {
            float v = vals[tt];
#pragma unroll
            for (int off = 32; off > 0; off >>= 1) v += __shfl_down(v, off);
            if ((t & 63) == 0) atomicAdd(&mom[tt * MSTR], v * 0.25f);
        }
    }
}

// ---- Kernel 2: r6-verified out. r17: idx row loaded as 5x ushort4
// (rows are 40 B = 5 x 8 B, all offsets 8B-aligned); unpack to NAMED
// values with static indices; fx..fd math and j-order unchanged.
__global__ __launch_bounds__(BLK)
void out_kernel(const float* __restrict__ pos,
                const float* __restrict__ W,
                const float* __restrict__ bias,
                const float* __restrict__ gamma,
                const float* __restrict__ beta,
                const unsigned short* __restrict__ idx_in,
                const float* __restrict__ mom,
                float* __restrict__ out) {
    __shared__ float sWp[COUT][4];
    __shared__ float sbp[COUT];

    if (threadIdx.x < COUT) {
        const int o = threadIdx.x;
        double S1[4], s2v[10];
#pragma unroll
        for (int tt = 0; tt < 4; ++tt)  S1[tt]  = (double)mom[tt * MSTR];
#pragma unroll
        for (int tt = 0; tt < 10; ++tt) s2v[tt] = (double)mom[(4 + tt) * MSTR];
        const double M = (double)NB * NP * KNN;
        double mean[4];
#pragma unroll
        for (int c = 0; c < 4; ++c) mean[c] = S1[c] / M;
        double E2[4][4];
        E2[0][0] = s2v[0]; E2[0][1] = E2[1][0] = s2v[1];
        E2[0][2] = E2[2][0] = s2v[2]; E2[0][3] = E2[3][0] = s2v[3];
        E2[1][1] = s2v[4]; E2[1][2] = E2[2][1] = s2v[5];
        E2[1][3] = E2[3][1] = s2v[6];
        E2[2][2] = s2v[7]; E2[2][3] = E2[3][2] = s2v[8];
        E2[3][3] = s2v[9];
        double w[4];
#pragma unroll
        for (int c = 0; c < 4; ++c) w[c] = (double)W[o * 4 + c];
        const double bo = (double)bias[o];
        double mu = bo;
#pragma unroll
        for (int c = 0; c < 4; ++c) mu += w[c] * mean[c];
        double var = 0.0;
#pragma unroll
        for (int c = 0; c < 4; ++c)
#pragma unroll
            for (int c2 = 0; c2 < 4; ++c2)
                var += w[c] * w[c2] * (E2[c][c2] / M - mean[c] * mean[c2]);
        const double scale = (double)gamma[o] / sqrt(var + 1e-5);
#pragma unroll
        for (int c = 0; c < 4; ++c) sWp[o][c] = (float)(w[c] * scale);
        sbp[o] = (float)((bo - mu) * scale + (double)beta[o]);
    }
    __syncthreads();

    const int t  = threadIdx.x;
    const int gq = blockIdx.x * (BLK / 4) + (t >> 2);  // global query
    const int b  = gq / NP, n = gq % NP;
    const int c0 = (t & 3) * 16;                       // my 16 channels
    const float* pb = pos + (size_t)b * NP * 3;
    const float qx = pb[3 * n], qy = pb[3 * n + 1], qz = pb[3 * n + 2];

    // vectorized idx row load: 5 x 8B, offsets gq*40 all = 0 mod 8
    const ushort4* ip4 =
        reinterpret_cast<const ushort4*>(idx_in + (size_t)gq * KNN);
    const ushort4 v0 = ip4[0], v1 = ip4[1], v2 = ip4[2], v3 = ip4[3],
                  v4 = ip4[4];
    const unsigned short mj[KNN] = {v0.x, v0.y, v0.z, v0.w,
                                    v1.x, v1.y, v1.z, v1.w,
                                    v2.x, v2.y, v2.z, v2.w,
                                    v3.x, v3.y, v3.z, v3.w,
                                    v4.x, v4.y, v4.z, v4.w};

    float fx[KNN], fy[KNN], fz[KNN], fd[KNN];
#pragma unroll
    for (int j = 0; j < KNN; ++j) {
        const int m = mj[j];                       // static j -> register idx
        const float dx = __fsub_rn(pb[3 * m], qx);
        const float dy = __fsub_rn(pb[3 * m + 1], qy);
        const float dz = __fsub_rn(pb[3 * m + 2], qz);
        fx[j] = dx; fy[j] = dy; fz[j] = dz;
        fd[j] = sqrtf(__fadd_rn(
            __fadd_rn(__fmul_rn(dx, dx), __fmul_rn(dy, dy)), __fmul_rn(dz, dz)));
    }

    float* ob = out + (size_t)gq * COUT + c0;
    const float inv = 1.0f / (float)KNN;
#pragma unroll
    for (int o = 0; o < 16; o += 4) {
        float acc[4];
#pragma unroll
        for (int qq = 0; qq < 4; ++qq) {
            const float w0 = sWp[c0 + o + qq][0], w1 = sWp[c0 + o + qq][1];
            const float w2 = sWp[c0 + o + qq][2], w3 = sWp[c0 + o + qq][3];
            const float bb = sbp[c0 + o + qq];
            float a = 0.f;
#pragma unroll
            for (int j = 0; j < KNN; ++j) {
                float y = fmaf(fx[j], w0,
                          fmaf(fy[j], w1, fmaf(fz[j], w2, fmaf(fd[j], w3, bb))));
                a += fmaxf(y, 0.f);
            }
            acc[qq] = a * inv;
        }
        float4 p = {acc[0], acc[1], acc[2], acc[3]};
        *reinterpret_cast<float4*>(ob + o) = p;
    }
}

extern "C" void kernel_launch(void* const* d_in, const int* in_sizes, int n_in,
                              void* d_out, int out_size, void* d_ws, size_t ws_size,
                              hipStream_t stream) {
    (void)in_sizes; (void)n_in; (void)out_size; (void)ws_size;
    const float* pos   = (const float*)d_in[1];   // d_in[0] = x (unused by math)
    const float* W     = (const float*)d_in[2];
    const float* bias  = (const float*)d_in[3];
    const float* gamma = (const float*)d_in[4];
    const float* beta  = (const float*)d_in[5];
    float* out = (float*)d_out;

    float* mom = (float*)d_ws;                                    // 14 x 64 B
    unsigned short* idxws = (unsigned short*)((char*)d_ws + 1024); // 1.31 MB

    hipMemsetAsync(mom, 0, NMOM * MSTR * sizeof(float), stream);
    knn_kernel<<<NBLK1, BLK, 0, stream>>>(pos, idxws, mom);
    out_kernel<<<NBLK2, BLK, 0, stream>>>(pos, W, bias, gamma, beta,
                                          idxws, mom, out);
}